// Round 15
// baseline (265.708 us; speedup 1.0000x reference)
//
#include <hip/hip_runtime.h>
#include <hip/hip_bf16.h>

#define NT 4096   // tokens
#define DM 1024   // d_model
#define DH 4096   // d_hidden
#define NE 8      // experts

#define BM 128
#define BN 128
#define BK 32
#define MAXT 40      // max padded M-tiles
#define MAXROWS 5120 // 40*128
#define KSPL2 2      // split-K for GEMM2 (K-window 2048)
#define BKP 40       // padded B LDS k-stride (80 B)

typedef short bf16x8 __attribute__((ext_vector_type(8)));
typedef float f32x4 __attribute__((ext_vector_type(4)));
typedef float f4 __attribute__((ext_vector_type(4)));

// meta ints at ws base
#define MI_COUNTS 0
#define MI_POFF   16
#define MI_NTILES 32
#define MI_TILEE  48
#define MI_TILER  112
#define MI_TILES0 176

#define O_BUCKET 1024ull
#define O_XB  (O_BUCKET + (size_t)NE * NT * 4)
#define O_H   (O_XB + (size_t)NT * DM * 2)                     // +8 MB
#define O_P   (O_H + (size_t)MAXROWS * DH * 2)                 // +40 MB
#define WS_NEED (O_P + (size_t)KSPL2 * MAXROWS * DM * 4)       // ~90 MiB

static __device__ __forceinline__ unsigned short f2bf(float f) {
  union { __hip_bfloat16 h; unsigned short u; } cv;
  cv.h = __float2bfloat16(f);
  return cv.u;
}

static __device__ __forceinline__ void gload16(const void* g, void* l) {
  __builtin_amdgcn_global_load_lds(
      (const __attribute__((address_space(1))) void*)g,
      (__attribute__((address_space(3))) void*)l, 16, 0, 0);
}

// ---------------------------------------------------------------------------
// Gate wave body: 8 logits (double accum -> first-max argmax), bucket
// scatter, x -> bf16.
// ---------------------------------------------------------------------------
static __device__ __forceinline__ void gate_body(
    const float* __restrict__ x, const float* __restrict__ gw,
    const float* __restrict__ gb, int* __restrict__ counts,
    int* __restrict__ bucket, __hip_bfloat16* __restrict__ xb, int bid) {
  const int tid = threadIdx.x;
  const int wid = tid >> 6;
  const int lane = tid & 63;
  const int t = bid * 4 + wid;

  const f4* xrow = (const f4*)(x + (size_t)t * DM);
  ushort4* xbrow = (ushort4*)(xb + (size_t)t * DM);

  double part[NE];
#pragma unroll
  for (int e = 0; e < NE; ++e) part[e] = 0.0;

#pragma unroll
  for (int q = 0; q < 4; ++q) {
    f4 v = xrow[q * 64 + lane];
    ushort4 s;
    s.x = f2bf(v[0]); s.y = f2bf(v[1]); s.z = f2bf(v[2]); s.w = f2bf(v[3]);
    xbrow[q * 64 + lane] = s;
#pragma unroll
    for (int e = 0; e < NE; ++e) {
      f4 w = ((const f4*)(gw + (size_t)e * DM))[q * 64 + lane];
      part[e] += (double)v[0] * w[0] + (double)v[1] * w[1] +
                 (double)v[2] * w[2] + (double)v[3] * w[3];
    }
  }
#pragma unroll
  for (int off = 32; off; off >>= 1) {
#pragma unroll
    for (int e = 0; e < NE; ++e) part[e] += __shfl_down(part[e], off);
  }
  if (lane == 0) {
    double best = part[0] + (double)gb[0];
    int bi = 0;
#pragma unroll
    for (int e = 1; e < NE; ++e) {
      double le = part[e] + (double)gb[e];
      if (le > best) { best = le; bi = e; }
    }
    int pos = atomicAdd(&counts[bi], 1);
    bucket[bi * NT + pos] = t;
  }
}

__global__ __launch_bounds__(256) void gate_route_kernel(
    const float* __restrict__ x, const float* __restrict__ gw,
    const float* __restrict__ gb, int* __restrict__ counts,
    int* __restrict__ bucket, __hip_bfloat16* __restrict__ xb) {
  gate_body(x, gw, gb, counts, bucket, xb, blockIdx.x);
}

// ---------------------------------------------------------------------------
// Prefix + padded tile table + bucket padding.
// ---------------------------------------------------------------------------
__global__ void prefix_kernel(int* __restrict__ meta, int* __restrict__ bucket) {
  if (threadIdx.x == 0) {
    int r = 0, nt = 0;
    for (int e = 0; e < NE; ++e) {
      meta[MI_POFF + e] = r;
      const int cnt = meta[MI_COUNTS + e];
      const int T = (cnt + BM - 1) / BM;
      for (int j = 0; j < T; ++j) {
        meta[MI_TILEE + nt] = e;
        meta[MI_TILER + nt] = r + j * BM;
        meta[MI_TILES0 + nt] = j * BM;
        ++nt;
      }
      r += T * BM;
    }
    meta[MI_POFF + NE] = r;
    meta[MI_NTILES] = nt;
  }
  __syncthreads();
  for (int e = 0; e < NE; ++e) {
    const int cnt = meta[MI_COUNTS + e];
    if (cnt == 0) continue;
    const int padTo = ((cnt + BM - 1) / BM) * BM;
    const int last = bucket[e * NT + cnt - 1];
    for (int i = cnt + threadIdx.x; i < padTo; i += blockDim.x)
      bucket[e * NT + i] = last;
  }
}

// ---------------------------------------------------------------------------
// Unified fp32-weight routed GEMM (no pre-convert anywhere).
// A (bf16) via global_load_lds into As[2][128][32].
// B (fp32 W [K][N]) staged per K-step: 16 coalesced dword loads/thread
// (prefetched TWO steps ahead of use), cvt, 4 ushort4 transposed writes into
// Bs[2][128][BKP]. ONE barrier per K-step:
//   BWRITE(buf^1)[tile kt+1] ; ASTAGE(buf^1, kt+1) ; BLOAD(kt+2) ;
//   COMPUTE(buf) ; __syncthreads()
// Readers of buf^1 finished before the PREVIOUS barrier, so the writes are
// safe; the barrier's vmcnt/lgkm drain publishes As/Bs[buf^1]; BLOAD issues
// early so the 16 MFMAs cover its latency.
// MODE 0: A = xb gathered via padded bucket, W = w1, K=1024 (32 steps),
//         N = DH, out = relu(acc+b1) -> h bf16 (padded-row order).
// MODE 1: A = h rows direct, W = w2, K-window kq*2048 (64 steps), N = DM,
//         out = fp32 partials P[kq].
// ---------------------------------------------------------------------------
template <int MODE>
static __device__ __forceinline__ void gemm_f32b(
    char* smem, int b, const __hip_bfloat16* __restrict__ A,
    const float* __restrict__ W, const float* __restrict__ biasAll,
    const int* __restrict__ meta, const int* __restrict__ bucket,
    void* __restrict__ Out) {
  auto As = reinterpret_cast<__hip_bfloat16(*)[BM][BK]>(smem);
  auto Bs = reinterpret_cast<__hip_bfloat16(*)[BN][BKP]>(smem + 16384);

  const int xcd = b & 7;
  const int idx = b >> 3;
  int tile, ntile, kq;
  if (MODE == 0) {
    const int grp = idx / MAXT;        // 0..3
    tile = idx - grp * MAXT;
    ntile = xcd * 4 + grp;             // 32 ntiles, 4 per XCD
    kq = 0;
  } else {
    const int grp = idx / MAXT;        // 0..1
    tile = idx - grp * MAXT;
    const int np = xcd * 2 + grp;      // 16 (ntile,kq) pairs, 2 per XCD
    ntile = np >> 1;
    kq = np & 1;
  }
  if (tile >= meta[MI_NTILES]) return;

  const int e = meta[MI_TILEE + tile];
  const int row0 = meta[MI_TILER + tile];
  const int s0 = meta[MI_TILES0 + tile];
  const int n0 = ntile * BN;
  const int N = (MODE == 0) ? DH : DM;
  const int Ktot = (MODE == 0) ? DM : DH;
  const int KTM = (MODE == 0) ? 32 : 64;
  const int kbase = (MODE == 0) ? 0 : kq * (DH / KSPL2);

  const int tid = threadIdx.x;
  const int lane = tid & 63;
  const int wid = tid >> 6;
  const int lr = lane >> 2, lc = lane & 3;

  const __hip_bfloat16 *aP0, *aP1;
  if (MODE == 0) {
    aP0 = A + (size_t)bucket[e * NT + s0 + 32 * wid + lr] * DM + lc * 8;
    aP1 = A + (size_t)bucket[e * NT + s0 + 32 * wid + 16 + lr] * DM + lc * 8;
  } else {
    aP0 = A + (size_t)(row0 + 32 * wid + lr) * DH + kbase + lc * 8;
    aP1 = A + (size_t)(row0 + 32 * wid + 16 + lr) * DH + kbase + lc * 8;
  }

  // B staging: thread covers cols {bc,bc+32,bc+64,bc+96} x k-rows bk0..bk0+3
  const int bc = tid & 31;
  const int bk0 = (tid >> 5) * 4;
  const float* Bp = W + (size_t)e * Ktot * N + (size_t)(kbase + bk0) * N +
                    n0 + bc;

  const int wm = (wid >> 1) * 64, wn = (wid & 1) * 64;
  const int fr = lane & 15, ks = lane >> 4;

  f32x4 acc[4][4];
#pragma unroll
  for (int m = 0; m < 4; ++m)
#pragma unroll
    for (int n = 0; n < 4; ++n) acc[m][n] = (f32x4){0.f, 0.f, 0.f, 0.f};

  float rb[4][4];  // prefetched B tile (k-sub x col-group)

#define BLOAD(kt)                                                     \
  do {                                                                \
    const float* bbase = Bp + (size_t)(kt) * BK * N;                  \
    _Pragma("unroll") for (int i = 0; i < 4; ++i)                     \
        _Pragma("unroll") for (int j = 0; j < 4; ++j)                 \
            rb[i][j] = bbase[(size_t)i * N + 32 * j];                 \
  } while (0)

#define BWRITE(bf)                                                    \
  do {                                                                \
    _Pragma("unroll") for (int j = 0; j < 4; ++j) {                   \
      ushort4 w;                                                      \
      w.x = f2bf(rb[0][j]); w.y = f2bf(rb[1][j]);                     \
      w.z = f2bf(rb[2][j]); w.w = f2bf(rb[3][j]);                     \
      *(ushort4*)&Bs[bf][bc + 32 * j][bk0] = w;                       \
    }                                                                 \
  } while (0)

#define ASTAGE(bf, kt)                                                \
  do {                                                                \
    gload16(aP0 + (size_t)(kt) * BK, &As[bf][32 * wid][0]);           \
    gload16(aP1 + (size_t)(kt) * BK, &As[bf][32 * wid + 16][0]);      \
  } while (0)

#define COMPUTE(bf)                                                          \
  do {                                                                       \
    bf16x8 afr[4], bfr[4];                                                   \
    _Pragma("unroll") for (int m = 0; m < 4; ++m)                            \
        afr[m] = *(const bf16x8*)&As[bf][wm + m * 16 + fr][ks * 8];          \
    _Pragma("unroll") for (int n = 0; n < 4; ++n)                            \
        bfr[n] = *(const bf16x8*)&Bs[bf][wn + n * 16 + fr][ks * 8];          \
    _Pragma("unroll") for (int m = 0; m < 4; ++m)                            \
        _Pragma("unroll") for (int n = 0; n < 4; ++n)                        \
            acc[m][n] = __builtin_amdgcn_mfma_f32_16x16x32_bf16(             \
                afr[m], bfr[n], acc[m][n], 0, 0, 0);                         \
  } while (0)

  // prologue: Bs[0]/As[0] ready after one barrier; rb holds tile 1
  BLOAD(0);
  ASTAGE(0, 0);
  BWRITE(0);
  BLOAD(1);
  __syncthreads();

  for (int kt = 0; kt < KTM; ++kt) {
    const int buf = kt & 1;
    if (kt + 1 < KTM) {
      BWRITE(buf ^ 1);              // tile kt+1 (readers done @ prev barrier)
      ASTAGE(buf ^ 1, kt + 1);      // flies under MFMAs
      if (kt + 2 < KTM) BLOAD(kt + 2);  // issued early; MFMAs cover latency
    }
    COMPUTE(buf);
    __syncthreads();                // publish As/Bs[buf^1]; drain loads
  }
#undef BLOAD
#undef BWRITE
#undef ASTAGE
#undef COMPUTE

  if (MODE == 0) {
    const float* bias = biasAll + (size_t)e * DH;
    __hip_bfloat16* Hout = (__hip_bfloat16*)Out;
#pragma unroll
    for (int m = 0; m < 4; ++m)
#pragma unroll
      for (int r = 0; r < 4; ++r) {
        const int row = wm + m * 16 + ks * 4 + r;
        __hip_bfloat16* orow = Hout + (size_t)(row0 + row) * DH;
#pragma unroll
        for (int n = 0; n < 4; ++n) {
          const int col = n0 + wn + n * 16 + fr;
          float v = acc[m][n][r] + bias[col];
          orow[col] = __float2bfloat16(v > 0.f ? v : 0.f);
        }
      }
  } else {
    float* Pout = (float*)Out + (size_t)kq * MAXROWS * DM;
#pragma unroll
    for (int m = 0; m < 4; ++m)
#pragma unroll
      for (int r = 0; r < 4; ++r) {
        const int row = wm + m * 16 + ks * 4 + r;
        float* orow = Pout + (size_t)(row0 + row) * DM;
#pragma unroll
        for (int n = 0; n < 4; ++n) {
          const int col = n0 + wn + n * 16 + fr;
          orow[col] = acc[m][n][r];
        }
      }
  }
}

__global__ __launch_bounds__(256, 2) void gemm1f_kernel(
    const __hip_bfloat16* __restrict__ xb, const float* __restrict__ w1,
    const float* __restrict__ b1, const int* __restrict__ meta,
    const int* __restrict__ bucket, __hip_bfloat16* __restrict__ h) {
  __shared__ __align__(16) char smem[36864];
  gemm_f32b<0>(smem, blockIdx.x, xb, w1, b1, meta, bucket, (void*)h);
}

__global__ __launch_bounds__(256, 2) void gemm2f_kernel(
    const __hip_bfloat16* __restrict__ h, const float* __restrict__ w2,
    const int* __restrict__ meta, const int* __restrict__ bucket,
    float* __restrict__ P) {
  __shared__ __align__(16) char smem[36864];
  gemm_f32b<1>(smem, blockIdx.x, h, w2, nullptr, meta, bucket, (void*)P);
}

// ---------------------------------------------------------------------------
// Reduce split-K partials, add b2, scatter padded-row -> token.
// ---------------------------------------------------------------------------
__global__ __launch_bounds__(256) void reduce_out_kernel(
    const float* __restrict__ P, const float* __restrict__ b2,
    const int* __restrict__ meta, const int* __restrict__ bucket,
    float* __restrict__ out) {
  const int gs = blockIdx.x;
  if (gs >= meta[MI_POFF + NE]) return;
  int e = 0;
#pragma unroll
  for (int i = 1; i < NE; ++i) e = (gs >= meta[MI_POFF + i]) ? i : e;
  const int i = gs - meta[MI_POFF + e];
  if (i >= meta[MI_COUNTS + e]) return;  // pad row
  const int tok = bucket[e * NT + i];
  const int c = threadIdx.x * 4;
  float4 v = *(const float4*)(P + (size_t)gs * DM + c);
#pragma unroll
  for (int q = 1; q < KSPL2; ++q) {
    float4 p = *(const float4*)(P + ((size_t)q * MAXROWS + gs) * DM + c);
    v.x += p.x; v.y += p.y; v.z += p.z; v.w += p.w;
  }
  float4 b = *(const float4*)(b2 + (size_t)e * DM + c);
  v.x += b.x; v.y += b.y; v.z += b.z; v.w += b.w;
  *(float4*)(out + (size_t)tok * DM + c) = v;
}

// ---------------------------------------------------------------------------
// Fallback path (small ws): round-1 proven kernels (raw fp32 weights).
// ---------------------------------------------------------------------------
template <bool RELU_BF16>
__global__ __launch_bounds__(256, 2) void moe_gemm_fallback(
    const __hip_bfloat16* __restrict__ Aall, int lda,
    const float* __restrict__ Ball, int K, int N,
    const float* __restrict__ biasAll, const int* __restrict__ counts,
    const int* __restrict__ bucket, void* __restrict__ Out, int ldo) {
  const int e = blockIdx.z;
  const int cnt = counts[e];
  const int m0 = blockIdx.y * BM;
  if (m0 >= cnt) return;
  const int n0 = blockIdx.x * BN;

  const float* Bp = Ball + (size_t)e * K * N;
  const float* bias = biasAll + (size_t)e * N;
  const int* buck = bucket + e * NT;

  __shared__ __align__(16) __hip_bfloat16 As[2][BM][BKP];
  __shared__ __align__(16) __hip_bfloat16 Bs[2][BN][BKP];

  const int tid = threadIdx.x;
  const int lane = tid & 63;
  const int wid = tid >> 6;
  const int wm = (wid >> 1) * 64;
  const int wn = (wid & 1) * 64;
  const int fr = lane & 15;
  const int ks = lane >> 4;

  const int ar = tid >> 1;
  const int ah = tid & 1;
  const int atok = buck[min(m0 + ar, cnt - 1)];
  const __hip_bfloat16* aptr = Aall + (size_t)atok * lda + ah * 16;

  const int bc = tid & 31;
  const int bk0 = (tid >> 5) * 4;

  f32x4 acc[4][4];
#pragma unroll
  for (int m = 0; m < 4; ++m)
#pragma unroll
    for (int n = 0; n < 4; ++n) acc[m][n] = (f32x4){0.f, 0.f, 0.f, 0.f};

  const int KTf = K / BK;
  uint4 ra0, ra1;
  float rb[4][4];

  {
    const uint4* p = (const uint4*)(aptr);
    ra0 = p[0]; ra1 = p[1];
    const float* bbase = Bp + (size_t)bk0 * N + n0 + bc;
#pragma unroll
    for (int i = 0; i < 4; ++i)
#pragma unroll
      for (int j = 0; j < 4; ++j) rb[i][j] = bbase[(size_t)i * N + 32 * j];
  }
  {
    *(uint4*)&As[0][ar][ah * 16] = ra0;
    *(uint4*)&As[0][ar][ah * 16 + 8] = ra1;
#pragma unroll
    for (int j = 0; j < 4; ++j) {
      ushort4 w;
      w.x = f2bf(rb[0][j]); w.y = f2bf(rb[1][j]);
      w.z = f2bf(rb[2][j]); w.w = f2bf(rb[3][j]);
      *(ushort4*)&Bs[0][bc + 32 * j][bk0] = w;
    }
  }
  __syncthreads();

  for (int kt = 0; kt < KTf; ++kt) {
    const int buf = kt & 1;
    if (kt + 1 < KTf) {
      const uint4* p = (const uint4*)(aptr + (size_t)(kt + 1) * BK);
      ra0 = p[0]; ra1 = p[1];
      const float* bbase = Bp + (size_t)((kt + 1) * BK + bk0) * N + n0 + bc;
#pragma unroll
      for (int i = 0; i < 4; ++i)
#pragma unroll
        for (int j = 0; j < 4; ++j) rb[i][j] = bbase[(size_t)i * N + 32 * j];
    }

    bf16x8 afr[4], bfr[4];
#pragma unroll
    for (int m = 0; m < 4; ++m)
      afr[m] = *(const bf16x8*)&As[buf][wm + m * 16 + fr][ks * 8];
#pragma unroll
    for (int n = 0; n < 4; ++n)
      bfr[n] = *(const bf16x8*)&Bs[buf][wn + n * 16 + fr][ks * 8];
#pragma unroll
    for (int m = 0; m < 4; ++m)
#pragma unroll
      for (int n = 0; n < 4; ++n)
        acc[m][n] = __builtin_amdgcn_mfma_f32_16x16x32_bf16(afr[m], bfr[n],
                                                            acc[m][n], 0, 0, 0);

    __syncthreads();
    if (kt + 1 < KTf) {
      *(uint4*)&As[buf ^ 1][ar][ah * 16] = ra0;
      *(uint4*)&As[buf ^ 1][ar][ah * 16 + 8] = ra1;
#pragma unroll
      for (int j = 0; j < 4; ++j) {
        ushort4 w;
        w.x = f2bf(rb[0][j]); w.y = f2bf(rb[1][j]);
        w.z = f2bf(rb[2][j]); w.w = f2bf(rb[3][j]);
        *(ushort4*)&Bs[buf ^ 1][bc + 32 * j][bk0] = w;
      }
      __syncthreads();
    }
  }

  float* outF = (float*)Out;
  __hip_bfloat16* outB = (__hip_bfloat16*)Out;
#pragma unroll
  for (int m = 0; m < 4; ++m) {
#pragma unroll
    for (int r = 0; r < 4; ++r) {
      const int row = wm + m * 16 + ks * 4 + r;
      const int slot = m0 + row;
      if (slot < cnt) {
        const int tok = buck[slot];
#pragma unroll
        for (int n = 0; n < 4; ++n) {
          const int col = n0 + wn + n * 16 + fr;
          float v = acc[m][n][r] + bias[col];
          if (RELU_BF16) {
            v = v > 0.f ? v : 0.f;
            outB[(size_t)tok * ldo + col] = __float2bfloat16(v);
          } else {
            outF[(size_t)tok * ldo + col] = v;
          }
        }
      }
    }
  }
}

extern "C" void kernel_launch(void* const* d_in, const int* in_sizes, int n_in,
                              void* d_out, int out_size, void* d_ws,
                              size_t ws_size, hipStream_t stream) {
  const float* x = (const float*)d_in[0];
  const float* gw = (const float*)d_in[1];
  const float* gb = (const float*)d_in[2];
  const float* w1 = (const float*)d_in[3];
  const float* b1 = (const float*)d_in[4];
  const float* w2 = (const float*)d_in[5];
  const float* b2 = (const float*)d_in[6];
  (void)in_sizes; (void)n_in; (void)out_size;

  char* ws = (char*)d_ws;
  int* meta = (int*)ws;
  int* counts = meta + MI_COUNTS;
  int* bucket = (int*)(ws + O_BUCKET);
  __hip_bfloat16* xb = (__hip_bfloat16*)(ws + O_XB);
  __hip_bfloat16* h = (__hip_bfloat16*)(ws + O_H);
  float* P = (float*)(ws + O_P);

  hipMemsetAsync(ws, 0, 1024, stream);

  if (ws_size >= WS_NEED) {
    gate_route_kernel<<<NT / 4, 256, 0, stream>>>(x, gw, gb, counts, bucket,
                                                  xb);
    prefix_kernel<<<1, 256, 0, stream>>>(meta, bucket);
    gemm1f_kernel<<<8 * 4 * MAXT, 256, 0, stream>>>(xb, w1, b1, meta, bucket,
                                                    h);
    gemm2f_kernel<<<8 * 2 * MAXT, 256, 0, stream>>>(h, w2, meta, bucket, P);
    reduce_out_kernel<<<MAXROWS, 256, 0, stream>>>(P, b2, meta, bucket,
                                                   (float*)d_out);
  } else {
    gate_route_kernel<<<NT / 4, 256, 0, stream>>>(x, gw, gb, counts, bucket,
                                                  xb);
    dim3 g1(DH / BN, NT / BM, NE);
    moe_gemm_fallback<true><<<g1, 256, 0, stream>>>(
        xb, DM, w1, DM, DH, b1, counts, bucket, (void*)h, DH);
    dim3 g2(DM / BN, NT / BM, NE);
    moe_gemm_fallback<false><<<g2, 256, 0, stream>>>(
        h, DH, w2, DH, DM, b2, counts, bucket, d_out, DM);
  }
}

// Round 16
// 252.669 us; speedup vs baseline: 1.0516x; 1.0516x over previous
//
#include <hip/hip_runtime.h>
#include <hip/hip_bf16.h>

#define NT 4096   // tokens
#define DM 1024   // d_model
#define DH 4096   // d_hidden
#define NE 8      // experts

#define BM 128
#define BN 128
#define BK 32
#define MAXT 40      // max padded M-tiles
#define MAXROWS 5120 // 40*128
#define KSPL2 2      // split-K for GEMM2 (K-window 2048)
#define BKP 40       // padded B LDS k-stride (80 B)
#define G1B (8 * 4 * MAXT)  // gemm1 block count (1280)

typedef short bf16x8 __attribute__((ext_vector_type(8)));
typedef float f32x4 __attribute__((ext_vector_type(4)));
typedef float f4 __attribute__((ext_vector_type(4)));

// meta ints at ws base
#define MI_COUNTS 0
#define MI_POFF   16
#define MI_NTILES 32
#define MI_TILEE  48
#define MI_TILER  112
#define MI_TILES0 176

#define O_BUCKET 1024ull
#define O_XB  (O_BUCKET + (size_t)NE * NT * 4)
#define O_H   (O_XB + (size_t)NT * DM * 2)                     // +8 MB
#define O_W1T (O_H + (size_t)MAXROWS * DH * 2)                 // +40 MB (P alias)
#define O_W2T (O_W1T + (size_t)NE * DM * DH * 2)               // +64 MB
#define WS_NEED (O_W2T + (size_t)NE * DH * DM * 2)             // ~176 MiB
#define O_P   O_W1T   // split-K partials alias unused w1t region

static __device__ __forceinline__ unsigned short f2bf(float f) {
  union { __hip_bfloat16 h; unsigned short u; } cv;
  cv.h = __float2bfloat16(f);
  return cv.u;
}

static __device__ __forceinline__ void gload16(const void* g, void* l) {
  __builtin_amdgcn_global_load_lds(
      (const __attribute__((address_space(1))) void*)g,
      (__attribute__((address_space(3))) void*)l, 16, 0, 0);
}

// ---------------------------------------------------------------------------
// Tiled weight layout (w2t only): bf16 tiles [128 n'][32 k'] (8 KB),
// ordered [e][ntile][kt], kt fastest. convert_v4: 64k x 64n region -> halves
// of two k-tiles. Grid decode sweeps n fastest (DRAM page streams).
// ---------------------------------------------------------------------------
static __device__ __forceinline__ void convert_v4(
    const float* __restrict__ S, __hip_bfloat16* __restrict__ D, int N,
    int KTcnt, int kglob0, int nglob0, char* smem) {
  auto Ls = reinterpret_cast<__hip_bfloat16(*)[72]>(smem);  // [64][72]
  const int tid = threadIdx.x;
  const int c4 = tid & 15, rk = tid >> 4;
  const float* src = S + (size_t)(kglob0 + rk * 4) * N + nglob0 + c4 * 4;
  f4 v[4];
#pragma unroll
  for (int j = 0; j < 4; ++j) v[j] = *(const f4*)(src + (size_t)j * N);
#pragma unroll
  for (int i = 0; i < 4; ++i) {
    ushort4 w;
    w.x = f2bf(v[0][i]); w.y = f2bf(v[1][i]);
    w.z = f2bf(v[2][i]); w.w = f2bf(v[3][i]);
    *(ushort4*)&Ls[c4 * 4 + i][rk * 4] = w;
  }
  __syncthreads();
  const int r = tid >> 2, q = tid & 3;
  const int nt = nglob0 >> 7;
  const int npr = (nglob0 & 64) + r;
#pragma unroll
  for (int u = 0; u < 2; ++u) {
    const int g = q * 2 + u;
    const int kt = (kglob0 >> 5) + (g >> 2);
    uint4 w = *(const uint4*)&Ls[r][g * 8];
    *(uint4*)(D + ((size_t)nt * KTcnt + kt) * 4096 + npr * 32 + (g & 3) * 8) =
        w;
  }
}

// ---------------------------------------------------------------------------
// Gate wave body.
// ---------------------------------------------------------------------------
static __device__ __forceinline__ void gate_body(
    const float* __restrict__ x, const float* __restrict__ gw,
    const float* __restrict__ gb, int* __restrict__ counts,
    int* __restrict__ bucket, __hip_bfloat16* __restrict__ xb, int bid) {
  const int tid = threadIdx.x;
  const int wid = tid >> 6;
  const int lane = tid & 63;
  const int t = bid * 4 + wid;

  const f4* xrow = (const f4*)(x + (size_t)t * DM);
  ushort4* xbrow = (ushort4*)(xb + (size_t)t * DM);

  double part[NE];
#pragma unroll
  for (int e = 0; e < NE; ++e) part[e] = 0.0;

#pragma unroll
  for (int q = 0; q < 4; ++q) {
    f4 v = xrow[q * 64 + lane];
    ushort4 s;
    s.x = f2bf(v[0]); s.y = f2bf(v[1]); s.z = f2bf(v[2]); s.w = f2bf(v[3]);
    xbrow[q * 64 + lane] = s;
#pragma unroll
    for (int e = 0; e < NE; ++e) {
      f4 w = ((const f4*)(gw + (size_t)e * DM))[q * 64 + lane];
      part[e] += (double)v[0] * w[0] + (double)v[1] * w[1] +
                 (double)v[2] * w[2] + (double)v[3] * w[3];
    }
  }
#pragma unroll
  for (int off = 32; off; off >>= 1) {
#pragma unroll
    for (int e = 0; e < NE; ++e) part[e] += __shfl_down(part[e], off);
  }
  if (lane == 0) {
    double best = part[0] + (double)gb[0];
    int bi = 0;
#pragma unroll
    for (int e = 1; e < NE; ++e) {
      double le = part[e] + (double)gb[e];
      if (le > best) { best = le; bi = e; }
    }
    int pos = atomicAdd(&counts[bi], 1);
    bucket[bi * NT + pos] = t;
  }
}

__global__ __launch_bounds__(256) void gate_route_kernel(
    const float* __restrict__ x, const float* __restrict__ gw,
    const float* __restrict__ gb, int* __restrict__ counts,
    int* __restrict__ bucket, __hip_bfloat16* __restrict__ xb) {
  gate_body(x, gw, gb, counts, bucket, xb, blockIdx.x);
}

// ---------------------------------------------------------------------------
// Prefix + padded tile table + bucket padding.
// ---------------------------------------------------------------------------
__global__ void prefix_kernel(int* __restrict__ meta, int* __restrict__ bucket) {
  if (threadIdx.x == 0) {
    int r = 0, nt = 0;
    for (int e = 0; e < NE; ++e) {
      meta[MI_POFF + e] = r;
      const int cnt = meta[MI_COUNTS + e];
      const int T = (cnt + BM - 1) / BM;
      for (int j = 0; j < T; ++j) {
        meta[MI_TILEE + nt] = e;
        meta[MI_TILER + nt] = r + j * BM;
        meta[MI_TILES0 + nt] = j * BM;
        ++nt;
      }
      r += T * BM;
    }
    meta[MI_POFF + NE] = r;
    meta[MI_NTILES] = nt;
  }
  __syncthreads();
  for (int e = 0; e < NE; ++e) {
    const int cnt = meta[MI_COUNTS + e];
    if (cnt == 0) continue;
    const int padTo = ((cnt + BM - 1) / BM) * BM;
    const int last = bucket[e * NT + cnt - 1];
    for (int i = cnt + threadIdx.x; i < padTo; i += blockDim.x)
      bucket[e * NT + i] = last;
  }
}

// ---------------------------------------------------------------------------
// gemm1 body, fp32-B in-kernel convert, ONE barrier per K-step (r15 proven):
//   BWRITE(buf^1)[tile kt+1]; ASTAGE(buf^1,kt+1); BLOAD(kt+2); COMPUTE(buf);
//   __syncthreads()
// Readers of buf^1 finished before the previous barrier -> writes race-free;
// barrier drain publishes As/Bs[buf^1]; early BLOAD hides under the MFMAs.
// ---------------------------------------------------------------------------
static __device__ __forceinline__ void gemm1_body_f32b(
    char* smem, int b, const __hip_bfloat16* __restrict__ A,
    const float* __restrict__ w1, const float* __restrict__ biasAll,
    const int* __restrict__ meta, const int* __restrict__ bucket,
    __hip_bfloat16* __restrict__ Hout) {
  auto As = reinterpret_cast<__hip_bfloat16(*)[BM][BK]>(smem);
  auto Bs = reinterpret_cast<__hip_bfloat16(*)[BN][BKP]>(smem + 16384);

  const int xcd = b & 7;
  const int idx = b >> 3;
  const int grp = idx / MAXT;        // 0..3
  const int tile = idx - grp * MAXT;
  const int ntile = xcd * 4 + grp;   // 32 ntiles, 4 per XCD
  if (tile >= meta[MI_NTILES]) return;

  const int e = meta[MI_TILEE + tile];
  const int row0 = meta[MI_TILER + tile];
  const int s0 = meta[MI_TILES0 + tile];
  const int n0 = ntile * BN;

  const int tid = threadIdx.x;
  const int lane = tid & 63;
  const int wid = tid >> 6;
  const int lr = lane >> 2, lc = lane & 3;

  const __hip_bfloat16* aP0 =
      A + (size_t)bucket[e * NT + s0 + 32 * wid + lr] * DM + lc * 8;
  const __hip_bfloat16* aP1 =
      A + (size_t)bucket[e * NT + s0 + 32 * wid + 16 + lr] * DM + lc * 8;

  const int bc = tid & 31;
  const int bk0 = (tid >> 5) * 4;
  const float* Bp = w1 + (size_t)e * DM * DH + n0 + bc;

  const int wm = (wid >> 1) * 64, wn = (wid & 1) * 64;
  const int fr = lane & 15, ks = lane >> 4;

  f32x4 acc[4][4];
#pragma unroll
  for (int m = 0; m < 4; ++m)
#pragma unroll
    for (int n = 0; n < 4; ++n) acc[m][n] = (f32x4){0.f, 0.f, 0.f, 0.f};

  float rb[4][4];  // prefetched B tile (k-sub x col-group)

#define BLOAD(kt)                                                     \
  do {                                                                \
    const float* bbase = Bp + (size_t)((kt) * BK + bk0) * DH;         \
    _Pragma("unroll") for (int i = 0; i < 4; ++i)                     \
        _Pragma("unroll") for (int j = 0; j < 4; ++j)                 \
            rb[i][j] = bbase[(size_t)i * DH + 32 * j];                \
  } while (0)

#define BWRITE(bf)                                                    \
  do {                                                                \
    _Pragma("unroll") for (int j = 0; j < 4; ++j) {                   \
      ushort4 w;                                                      \
      w.x = f2bf(rb[0][j]); w.y = f2bf(rb[1][j]);                     \
      w.z = f2bf(rb[2][j]); w.w = f2bf(rb[3][j]);                     \
      *(ushort4*)&Bs[bf][bc + 32 * j][bk0] = w;                       \
    }                                                                 \
  } while (0)

#define ASTAGE(bf, kt)                                                \
  do {                                                                \
    gload16(aP0 + (size_t)(kt) * BK, &As[bf][32 * wid][0]);           \
    gload16(aP1 + (size_t)(kt) * BK, &As[bf][32 * wid + 16][0]);      \
  } while (0)

#define COMPUTE(bf)                                                          \
  do {                                                                       \
    bf16x8 afr[4], bfr[4];                                                   \
    _Pragma("unroll") for (int m = 0; m < 4; ++m)                            \
        afr[m] = *(const bf16x8*)&As[bf][wm + m * 16 + fr][ks * 8];          \
    _Pragma("unroll") for (int n = 0; n < 4; ++n)                            \
        bfr[n] = *(const bf16x8*)&Bs[bf][wn + n * 16 + fr][ks * 8];          \
    _Pragma("unroll") for (int m = 0; m < 4; ++m)                            \
        _Pragma("unroll") for (int n = 0; n < 4; ++n)                        \
            acc[m][n] = __builtin_amdgcn_mfma_f32_16x16x32_bf16(             \
                afr[m], bfr[n], acc[m][n], 0, 0, 0);                         \
  } while (0)

  // prologue: Bs[0]/As[0] ready after one barrier; rb holds tile 1
  BLOAD(0);
  ASTAGE(0, 0);
  BWRITE(0);
  BLOAD(1);
  __syncthreads();

  for (int kt = 0; kt < 32; ++kt) {
    const int buf = kt & 1;
    if (kt + 1 < 32) {
      BWRITE(buf ^ 1);              // tile kt+1 (readers done @ prev barrier)
      ASTAGE(buf ^ 1, kt + 1);      // flies under MFMAs
      if (kt + 2 < 32) BLOAD(kt + 2);
    }
    COMPUTE(buf);
    __syncthreads();                // publish As/Bs[buf^1]; drain loads
  }
#undef BLOAD
#undef BWRITE
#undef ASTAGE
#undef COMPUTE

  const float* bias = biasAll + (size_t)e * DH;
#pragma unroll
  for (int m = 0; m < 4; ++m)
#pragma unroll
    for (int r = 0; r < 4; ++r) {
      const int row = wm + m * 16 + ks * 4 + r;
      __hip_bfloat16* orow = Hout + (size_t)(row0 + row) * DH;
#pragma unroll
      for (int n = 0; n < 4; ++n) {
        const int col = n0 + wn + n * 16 + fr;
        float v = acc[m][n][r] + bias[col];
        orow[col] = __float2bfloat16(v > 0.f ? v : 0.f);
      }
    }
}

// ---------------------------------------------------------------------------
// gemm2 body (r13/r14 proven): tiled bf16 w2t, gl_lds both operands, split-K.
// ---------------------------------------------------------------------------
static __device__ __forceinline__ void gemm2_body(
    char* smem, int b, const __hip_bfloat16* __restrict__ A,
    const __hip_bfloat16* __restrict__ B, const int* __restrict__ meta,
    float* __restrict__ Pout0) {
  auto As = reinterpret_cast<__hip_bfloat16(*)[BM][BK]>(smem);
  auto Bs = reinterpret_cast<__hip_bfloat16(*)[BN][BK]>(smem + 16384);

  const int xcd = b & 7;
  const int idx = b >> 3;
  const int grp = idx / MAXT;
  const int tile = idx - grp * MAXT;
  const int np = xcd * 2 + grp;      // 16 (ntile,kq) pairs, 2 per XCD
  const int ntile = np >> 1;
  const int kq = np & 1;
  if (tile >= meta[MI_NTILES]) return;

  const int e = meta[MI_TILEE + tile];
  const int row0 = meta[MI_TILER + tile];
  const int n0 = ntile * BN;
  const int kbase = kq * (DH / KSPL2);
  const int KTcnt = DH / 32;  // 128
  const int ktb = kq * 64;

  const int tid = threadIdx.x;
  const int lane = tid & 63;
  const int wid = tid >> 6;
  const int lr = lane >> 2, lc = lane & 3;

  const __hip_bfloat16* aP0 =
      A + (size_t)(row0 + 32 * wid + lr) * DH + kbase + lc * 8;
  const __hip_bfloat16* aP1 =
      A + (size_t)(row0 + 32 * wid + 16 + lr) * DH + kbase + lc * 8;
  const __hip_bfloat16* bP0 =
      B + (((size_t)e * (DM / 128) + ntile) * KTcnt + ktb) * 4096 +
      wid * 1024 + lane * 8;
  const __hip_bfloat16* bP1 = bP0 + 512;

  const int wm = (wid >> 1) * 64, wn = (wid & 1) * 64;
  const int fr = lane & 15, ks = lane >> 4;

  f32x4 acc[4][4];
#pragma unroll
  for (int m = 0; m < 4; ++m)
#pragma unroll
    for (int n = 0; n < 4; ++n) acc[m][n] = (f32x4){0.f, 0.f, 0.f, 0.f};

#define STAGE(bf, kt)                                              \
  do {                                                             \
    gload16(aP0 + (size_t)(kt) * BK, &As[bf][32 * wid][0]);        \
    gload16(aP1 + (size_t)(kt) * BK, &As[bf][32 * wid + 16][0]);   \
    gload16(bP0 + (size_t)(kt) * 4096, &Bs[bf][32 * wid][0]);      \
    gload16(bP1 + (size_t)(kt) * 4096, &Bs[bf][32 * wid + 16][0]); \
  } while (0)

  STAGE(0, 0);
  __syncthreads();

  for (int kt = 0; kt < 64; ++kt) {
    const int buf = kt & 1;
    if (kt + 1 < 64) STAGE(buf ^ 1, kt + 1);
    bf16x8 afr[4], bfr[4];
#pragma unroll
    for (int m = 0; m < 4; ++m)
      afr[m] = *(const bf16x8*)&As[buf][wm + m * 16 + fr][ks * 8];
#pragma unroll
    for (int n = 0; n < 4; ++n)
      bfr[n] = *(const bf16x8*)&Bs[buf][wn + n * 16 + fr][ks * 8];
#pragma unroll
    for (int m = 0; m < 4; ++m)
#pragma unroll
      for (int n = 0; n < 4; ++n)
        acc[m][n] = __builtin_amdgcn_mfma_f32_16x16x32_bf16(afr[m], bfr[n],
                                                            acc[m][n], 0, 0, 0);
    __syncthreads();
  }
#undef STAGE

  float* Pout = Pout0 + (size_t)kq * MAXROWS * DM;
#pragma unroll
  for (int m = 0; m < 4; ++m)
#pragma unroll
    for (int r = 0; r < 4; ++r) {
      const int row = wm + m * 16 + ks * 4 + r;
      float* orow = Pout + (size_t)(row0 + row) * DM;
#pragma unroll
      for (int n = 0; n < 4; ++n) {
        const int col = n0 + wn + n * 16 + fr;
        orow[col] = acc[m][n][r];
      }
    }
}

// ---------------------------------------------------------------------------
// Kernel: gemm1 fp32-B (blocks 0..G1B-1) + convert w2 tiled (G1B..+8191).
// ---------------------------------------------------------------------------
__global__ __launch_bounds__(256, 2) void gemm1f_cw2_kernel(
    const __hip_bfloat16* __restrict__ xb, const float* __restrict__ w1,
    const float* __restrict__ b1, const int* __restrict__ meta,
    const int* __restrict__ bucket, __hip_bfloat16* __restrict__ h,
    const float* __restrict__ w2, __hip_bfloat16* __restrict__ w2t) {
  __shared__ __align__(16) char smem[36864];  // As 16K + Bs 2*128*40*2=20.5K
  const int bid = blockIdx.x;
  if (bid < G1B) {
    gemm1_body_f32b(smem, bid, xb, w1, b1, meta, bucket, h);
    return;
  }
  const int id = bid - G1B;
  const int e = id >> 10;
  const int rem = id & 1023;           // 64 kg x 16 ng
  const int kglob0 = (rem >> 4) * 64;  // k slowest
  const int nglob0 = (rem & 15) * 64;  // n fastest
  convert_v4(w2 + (size_t)e * DH * DM, w2t + (size_t)e * DH * DM, DM,
             DH / 32, kglob0, nglob0, smem);
}

__global__ __launch_bounds__(256, 2) void gemm2_kernel(
    const __hip_bfloat16* __restrict__ h, const __hip_bfloat16* __restrict__ w2t,
    const int* __restrict__ meta, float* __restrict__ P) {
  __shared__ __align__(16) char smem[32768];
  gemm2_body(smem, blockIdx.x, h, w2t, meta, P);
}

// ---------------------------------------------------------------------------
// Reduce split-K partials, add b2, scatter padded-row -> token.
// ---------------------------------------------------------------------------
__global__ __launch_bounds__(256) void reduce_out_kernel(
    const float* __restrict__ P, const float* __restrict__ b2,
    const int* __restrict__ meta, const int* __restrict__ bucket,
    float* __restrict__ out) {
  const int gs = blockIdx.x;
  if (gs >= meta[MI_POFF + NE]) return;
  int e = 0;
#pragma unroll
  for (int i = 1; i < NE; ++i) e = (gs >= meta[MI_POFF + i]) ? i : e;
  const int i = gs - meta[MI_POFF + e];
  if (i >= meta[MI_COUNTS + e]) return;  // pad row
  const int tok = bucket[e * NT + i];
  const int c = threadIdx.x * 4;
  float4 v = *(const float4*)(P + (size_t)gs * DM + c);
#pragma unroll
  for (int q = 1; q < KSPL2; ++q) {
    float4 p = *(const float4*)(P + ((size_t)q * MAXROWS + gs) * DM + c);
    v.x += p.x; v.y += p.y; v.z += p.z; v.w += p.w;
  }
  float4 b = *(const float4*)(b2 + (size_t)e * DM + c);
  v.x += b.x; v.y += b.y; v.z += b.z; v.w += b.w;
  *(float4*)(out + (size_t)tok * DM + c) = v;
}

// ---------------------------------------------------------------------------
// Fallback path (small ws): round-1 proven kernels (raw fp32 weights).
// ---------------------------------------------------------------------------
template <bool RELU_BF16>
__global__ __launch_bounds__(256, 2) void moe_gemm_fallback(
    const __hip_bfloat16* __restrict__ Aall, int lda,
    const float* __restrict__ Ball, int K, int N,
    const float* __restrict__ biasAll, const int* __restrict__ counts,
    const int* __restrict__ bucket, void* __restrict__ Out, int ldo) {
  const int e = blockIdx.z;
  const int cnt = counts[e];
  const int m0 = blockIdx.y * BM;
  if (m0 >= cnt) return;
  const int n0 = blockIdx.x * BN;

  const float* Bp = Ball + (size_t)e * K * N;
  const float* bias = biasAll + (size_t)e * N;
  const int* buck = bucket + e * NT;

  __shared__ __align__(16) __hip_bfloat16 As[2][BM][BKP];
  __shared__ __align__(16) __hip_bfloat16 Bs[2][BN][BKP];

  const int tid = threadIdx.x;
  const int lane = tid & 63;
  const int wid = tid >> 6;
  const int wm = (wid >> 1) * 64;
  const int wn = (wid & 1) * 64;
  const int fr = lane & 15;
  const int ks = lane >> 4;

  const int ar = tid >> 1;
  const int ah = tid & 1;
  const int atok = buck[min(m0 + ar, cnt - 1)];
  const __hip_bfloat16* aptr = Aall + (size_t)atok * lda + ah * 16;

  const int bc = tid & 31;
  const int bk0 = (tid >> 5) * 4;

  f32x4 acc[4][4];
#pragma unroll
  for (int m = 0; m < 4; ++m)
#pragma unroll
    for (int n = 0; n < 4; ++n) acc[m][n] = (f32x4){0.f, 0.f, 0.f, 0.f};

  const int KTf = K / BK;
  uint4 ra0, ra1;
  float rb[4][4];

  {
    const uint4* p = (const uint4*)(aptr);
    ra0 = p[0]; ra1 = p[1];
    const float* bbase = Bp + (size_t)bk0 * N + n0 + bc;
#pragma unroll
    for (int i = 0; i < 4; ++i)
#pragma unroll
      for (int j = 0; j < 4; ++j) rb[i][j] = bbase[(size_t)i * N + 32 * j];
  }
  {
    *(uint4*)&As[0][ar][ah * 16] = ra0;
    *(uint4*)&As[0][ar][ah * 16 + 8] = ra1;
#pragma unroll
    for (int j = 0; j < 4; ++j) {
      ushort4 w;
      w.x = f2bf(rb[0][j]); w.y = f2bf(rb[1][j]);
      w.z = f2bf(rb[2][j]); w.w = f2bf(rb[3][j]);
      *(ushort4*)&Bs[0][bc + 32 * j][bk0] = w;
    }
  }
  __syncthreads();

  for (int kt = 0; kt < KTf; ++kt) {
    const int buf = kt & 1;
    if (kt + 1 < KTf) {
      const uint4* p = (const uint4*)(aptr + (size_t)(kt + 1) * BK);
      ra0 = p[0]; ra1 = p[1];
      const float* bbase = Bp + (size_t)((kt + 1) * BK + bk0) * N + n0 + bc;
#pragma unroll
      for (int i = 0; i < 4; ++i)
#pragma unroll
        for (int j = 0; j < 4; ++j) rb[i][j] = bbase[(size_t)i * N + 32 * j];
    }

    bf16x8 afr[4], bfr[4];
#pragma unroll
    for (int m = 0; m < 4; ++m)
      afr[m] = *(const bf16x8*)&As[buf][wm + m * 16 + fr][ks * 8];
#pragma unroll
    for (int n = 0; n < 4; ++n)
      bfr[n] = *(const bf16x8*)&Bs[buf][wn + n * 16 + fr][ks * 8];
#pragma unroll
    for (int m = 0; m < 4; ++m)
#pragma unroll
      for (int n = 0; n < 4; ++n)
        acc[m][n] = __builtin_amdgcn_mfma_f32_16x16x32_bf16(afr[m], bfr[n],
                                                            acc[m][n], 0, 0, 0);

    __syncthreads();
    if (kt + 1 < KTf) {
      *(uint4*)&As[buf ^ 1][ar][ah * 16] = ra0;
      *(uint4*)&As[buf ^ 1][ar][ah * 16 + 8] = ra1;
#pragma unroll
      for (int j = 0; j < 4; ++j) {
        ushort4 w;
        w.x = f2bf(rb[0][j]); w.y = f2bf(rb[1][j]);
        w.z = f2bf(rb[2][j]); w.w = f2bf(rb[3][j]);
        *(ushort4*)&Bs[buf ^ 1][bc + 32 * j][bk0] = w;
      }
      __syncthreads();
    }
  }

  float* outF = (float*)Out;
  __hip_bfloat16* outB = (__hip_bfloat16*)Out;
#pragma unroll
  for (int m = 0; m < 4; ++m) {
#pragma unroll
    for (int r = 0; r < 4; ++r) {
      const int row = wm + m * 16 + ks * 4 + r;
      const int slot = m0 + row;
      if (slot < cnt) {
        const int tok = buck[slot];
#pragma unroll
        for (int n = 0; n < 4; ++n) {
          const int col = n0 + wn + n * 16 + fr;
          float v = acc[m][n][r] + bias[col];
          if (RELU_BF16) {
            v = v > 0.f ? v : 0.f;
            outB[(size_t)tok * ldo + col] = __float2bfloat16(v);
          } else {
            outF[(size_t)tok * ldo + col] = v;
          }
        }
      }
    }
  }
}

extern "C" void kernel_launch(void* const* d_in, const int* in_sizes, int n_in,
                              void* d_out, int out_size, void* d_ws,
                              size_t ws_size, hipStream_t stream) {
  const float* x = (const float*)d_in[0];
  const float* gw = (const float*)d_in[1];
  const float* gb = (const float*)d_in[2];
  const float* w1 = (const float*)d_in[3];
  const float* b1 = (const float*)d_in[4];
  const float* w2 = (const float*)d_in[5];
  const float* b2 = (const float*)d_in[6];
  (void)in_sizes; (void)n_in; (void)out_size;

  char* ws = (char*)d_ws;
  int* meta = (int*)ws;
  int* counts = meta + MI_COUNTS;
  int* bucket = (int*)(ws + O_BUCKET);
  __hip_bfloat16* xb = (__hip_bfloat16*)(ws + O_XB);
  __hip_bfloat16* h = (__hip_bfloat16*)(ws + O_H);

  hipMemsetAsync(ws, 0, 1024, stream);

  if (ws_size >= WS_NEED) {
    __hip_bfloat16* w2t = (__hip_bfloat16*)(ws + O_W2T);
    float* P = (float*)(ws + O_P);

    gate_route_kernel<<<NT / 4, 256, 0, stream>>>(x, gw, gb, counts, bucket,
                                                  xb);
    prefix_kernel<<<1, 256, 0, stream>>>(meta, bucket);
    gemm1f_cw2_kernel<<<G1B + 8192, 256, 0, stream>>>(
        xb, w1, b1, meta, bucket, h, w2, w2t);
    gemm2_kernel<<<8 * 2 * MAXT, 256, 0, stream>>>(h, w2t, meta, P);
    reduce_out_kernel<<<MAXROWS, 256, 0, stream>>>(P, b2, meta, bucket,
                                                   (float*)d_out);
  } else {
    gate_route_kernel<<<NT / 4, 256, 0, stream>>>(x, gw, gb, counts, bucket,
                                                  xb);
    dim3 g1(DH / BN, NT / BM, NE);
    moe_gemm_fallback<true><<<g1, 256, 0, stream>>>(
        xb, DM, w1, DM, DH, b1, counts, bucket, (void*)h, DH);
    dim3 g2(DM / BN, NT / BM, NE);
    moe_gemm_fallback<false><<<g2, 256, 0, stream>>>(
        h, DH, w2, DH, DM, b2, counts, bucket, d_out, DM);
  }
}

// Round 17
// 250.774 us; speedup vs baseline: 1.0596x; 1.0076x over previous
//
#include <hip/hip_runtime.h>
#include <hip/hip_bf16.h>

#define NT 4096   // tokens
#define DM 1024   // d_model
#define DH 4096   // d_hidden
#define NE 8      // experts

#define BM 128
#define BN 128
#define BK 32
#define MAXT 40      // max padded M-tiles (worst skew 39)
#define MAXROWS 5120 // 40*128
#define KSPL2 2      // split-K for GEMM2 (K-window 2048)
#define BKP 40       // padded B LDS k-stride (80 B)
#define G1B (8 * 4 * MAXT)  // gemm1 block count (1280)

typedef short bf16x8 __attribute__((ext_vector_type(8)));
typedef float f32x4 __attribute__((ext_vector_type(4)));
typedef float f4 __attribute__((ext_vector_type(4)));

#define O_BUCKET 1024ull
#define O_XB  (O_BUCKET + (size_t)NE * NT * 4)
#define O_H   (O_XB + (size_t)NT * DM * 2)                     // +8 MB
#define O_W1T (O_H + (size_t)MAXROWS * DH * 2)                 // +40 MB (P alias)
#define O_W2T (O_W1T + (size_t)NE * DM * DH * 2)               // +64 MB
#define WS_NEED (O_W2T + (size_t)NE * DH * DM * 2)             // ~176 MiB
#define O_P   O_W1T   // split-K partials alias unused w1t region

static __device__ __forceinline__ unsigned short f2bf(float f) {
  union { __hip_bfloat16 h; unsigned short u; } cv;
  cv.h = __float2bfloat16(f);
  return cv.u;
}

static __device__ __forceinline__ void gload16(const void* g, void* l) {
  __builtin_amdgcn_global_load_lds(
      (const __attribute__((address_space(1))) void*)g,
      (__attribute__((address_space(3))) void*)l, 16, 0, 0);
}

// ---------------------------------------------------------------------------
// Inline tile-table decode from counts (replaces prefix_kernel): for a flat
// tile index, find (expert, padded row base, slot base, cnt). 8 scalar loads,
// L2-hot; uniform per block.
// ---------------------------------------------------------------------------
struct TileInfo { int e, row0, s0, cnt, valid; };
static __device__ __forceinline__ TileInfo tile_decode(
    const int* __restrict__ counts, int tile) {
  TileInfo ti;
  ti.valid = 0; ti.e = 0; ti.row0 = 0; ti.s0 = 0; ti.cnt = 0;
  int acc = 0, r = 0;
#pragma unroll
  for (int q = 0; q < NE; ++q) {
    const int c = counts[q];
    const int T = (c + BM - 1) >> 7;
    if (!ti.valid && tile < acc + T) {
      ti.e = q;
      ti.s0 = (tile - acc) * BM;
      ti.row0 = r + ti.s0;
      ti.cnt = c;
      ti.valid = 1;
    }
    acc += T;
    r += T * BM;
  }
  return ti;
}

// ---------------------------------------------------------------------------
// Tiled weight layout (w2t): bf16 tiles [128 n'][32 k'] (8 KB), ordered
// [e][ntile][kt], kt fastest. convert_v4: 64k x 64n region -> halves of two
// k-tiles. Grid decode sweeps n fastest (DRAM page streams).
// ---------------------------------------------------------------------------
static __device__ __forceinline__ void convert_v4(
    const float* __restrict__ S, __hip_bfloat16* __restrict__ D, int N,
    int KTcnt, int kglob0, int nglob0, char* smem) {
  auto Ls = reinterpret_cast<__hip_bfloat16(*)[72]>(smem);  // [64][72]
  const int tid = threadIdx.x;
  const int c4 = tid & 15, rk = tid >> 4;
  const float* src = S + (size_t)(kglob0 + rk * 4) * N + nglob0 + c4 * 4;
  f4 v[4];
#pragma unroll
  for (int j = 0; j < 4; ++j) v[j] = *(const f4*)(src + (size_t)j * N);
#pragma unroll
  for (int i = 0; i < 4; ++i) {
    ushort4 w;
    w.x = f2bf(v[0][i]); w.y = f2bf(v[1][i]);
    w.z = f2bf(v[2][i]); w.w = f2bf(v[3][i]);
    *(ushort4*)&Ls[c4 * 4 + i][rk * 4] = w;
  }
  __syncthreads();
  const int r = tid >> 2, q = tid & 3;
  const int nt = nglob0 >> 7;
  const int npr = (nglob0 & 64) + r;
#pragma unroll
  for (int u = 0; u < 2; ++u) {
    const int g = q * 2 + u;
    const int kt = (kglob0 >> 5) + (g >> 2);
    uint4 w = *(const uint4*)&Ls[r][g * 8];
    *(uint4*)(D + ((size_t)nt * KTcnt + kt) * 4096 + npr * 32 + (g & 3) * 8) =
        w;
  }
}

// ---------------------------------------------------------------------------
// Gate wave body.
// ---------------------------------------------------------------------------
static __device__ __forceinline__ void gate_body(
    const float* __restrict__ x, const float* __restrict__ gw,
    const float* __restrict__ gb, int* __restrict__ counts,
    int* __restrict__ bucket, __hip_bfloat16* __restrict__ xb, int bid) {
  const int tid = threadIdx.x;
  const int wid = tid >> 6;
  const int lane = tid & 63;
  const int t = bid * 4 + wid;

  const f4* xrow = (const f4*)(x + (size_t)t * DM);
  ushort4* xbrow = (ushort4*)(xb + (size_t)t * DM);

  double part[NE];
#pragma unroll
  for (int e = 0; e < NE; ++e) part[e] = 0.0;

#pragma unroll
  for (int q = 0; q < 4; ++q) {
    f4 v = xrow[q * 64 + lane];
    ushort4 s;
    s.x = f2bf(v[0]); s.y = f2bf(v[1]); s.z = f2bf(v[2]); s.w = f2bf(v[3]);
    xbrow[q * 64 + lane] = s;
#pragma unroll
    for (int e = 0; e < NE; ++e) {
      f4 w = ((const f4*)(gw + (size_t)e * DM))[q * 64 + lane];
      part[e] += (double)v[0] * w[0] + (double)v[1] * w[1] +
                 (double)v[2] * w[2] + (double)v[3] * w[3];
    }
  }
#pragma unroll
  for (int off = 32; off; off >>= 1) {
#pragma unroll
    for (int e = 0; e < NE; ++e) part[e] += __shfl_down(part[e], off);
  }
  if (lane == 0) {
    double best = part[0] + (double)gb[0];
    int bi = 0;
#pragma unroll
    for (int e = 1; e < NE; ++e) {
      double le = part[e] + (double)gb[e];
      if (le > best) { best = le; bi = e; }
    }
    int pos = atomicAdd(&counts[bi], 1);
    bucket[bi * NT + pos] = t;
  }
}

__global__ __launch_bounds__(256) void gate_route_kernel(
    const float* __restrict__ x, const float* __restrict__ gw,
    const float* __restrict__ gb, int* __restrict__ counts,
    int* __restrict__ bucket, __hip_bfloat16* __restrict__ xb) {
  gate_body(x, gw, gb, counts, bucket, xb, blockIdx.x);
}

// ---------------------------------------------------------------------------
// gemm1 body, fp32-B in-kernel convert, one barrier per K-step (r15/16):
// A gathered with clamped bucket index (no padding pass needed).
// ---------------------------------------------------------------------------
static __device__ __forceinline__ void gemm1_body_f32b(
    char* smem, int b, const __hip_bfloat16* __restrict__ A,
    const float* __restrict__ w1, const float* __restrict__ biasAll,
    const int* __restrict__ counts, const int* __restrict__ bucket,
    __hip_bfloat16* __restrict__ Hout) {
  auto As = reinterpret_cast<__hip_bfloat16(*)[BM][BK]>(smem);
  auto Bs = reinterpret_cast<__hip_bfloat16(*)[BN][BKP]>(smem + 16384);

  const int xcd = b & 7;
  const int idx = b >> 3;
  const int grp = idx / MAXT;        // 0..3
  const int tile = idx - grp * MAXT;
  const int ntile = xcd * 4 + grp;   // 32 ntiles, 4 per XCD
  const TileInfo ti = tile_decode(counts, tile);
  if (!ti.valid) return;
  const int e = ti.e, row0 = ti.row0, s0 = ti.s0, cnt = ti.cnt;
  const int n0 = ntile * BN;

  const int tid = threadIdx.x;
  const int lane = tid & 63;
  const int wid = tid >> 6;
  const int lr = lane >> 2, lc = lane & 3;

  const int sa0 = min(s0 + 32 * wid + lr, cnt - 1);
  const int sa1 = min(s0 + 32 * wid + 16 + lr, cnt - 1);
  const __hip_bfloat16* aP0 = A + (size_t)bucket[e * NT + sa0] * DM + lc * 8;
  const __hip_bfloat16* aP1 = A + (size_t)bucket[e * NT + sa1] * DM + lc * 8;

  const int bc = tid & 31;
  const int bk0 = (tid >> 5) * 4;
  const float* Bp = w1 + (size_t)e * DM * DH + n0 + bc;

  const int wm = (wid >> 1) * 64, wn = (wid & 1) * 64;
  const int fr = lane & 15, ks = lane >> 4;

  f32x4 acc[4][4];
#pragma unroll
  for (int m = 0; m < 4; ++m)
#pragma unroll
    for (int n = 0; n < 4; ++n) acc[m][n] = (f32x4){0.f, 0.f, 0.f, 0.f};

  float rb[4][4];

#define BLOAD(kt)                                                     \
  do {                                                                \
    const float* bbase = Bp + (size_t)((kt) * BK + bk0) * DH;         \
    _Pragma("unroll") for (int i = 0; i < 4; ++i)                     \
        _Pragma("unroll") for (int j = 0; j < 4; ++j)                 \
            rb[i][j] = bbase[(size_t)i * DH + 32 * j];                \
  } while (0)

#define BWRITE(bf)                                                    \
  do {                                                                \
    _Pragma("unroll") for (int j = 0; j < 4; ++j) {                   \
      ushort4 w;                                                      \
      w.x = f2bf(rb[0][j]); w.y = f2bf(rb[1][j]);                     \
      w.z = f2bf(rb[2][j]); w.w = f2bf(rb[3][j]);                     \
      *(ushort4*)&Bs[bf][bc + 32 * j][bk0] = w;                       \
    }                                                                 \
  } while (0)

#define ASTAGE(bf, kt)                                                \
  do {                                                                \
    gload16(aP0 + (size_t)(kt) * BK, &As[bf][32 * wid][0]);           \
    gload16(aP1 + (size_t)(kt) * BK, &As[bf][32 * wid + 16][0]);      \
  } while (0)

#define COMPUTE(bf)                                                          \
  do {                                                                       \
    bf16x8 afr[4], bfr[4];                                                   \
    _Pragma("unroll") for (int m = 0; m < 4; ++m)                            \
        afr[m] = *(const bf16x8*)&As[bf][wm + m * 16 + fr][ks * 8];          \
    _Pragma("unroll") for (int n = 0; n < 4; ++n)                            \
        bfr[n] = *(const bf16x8*)&Bs[bf][wn + n * 16 + fr][ks * 8];          \
    _Pragma("unroll") for (int m = 0; m < 4; ++m)                            \
        _Pragma("unroll") for (int n = 0; n < 4; ++n)                        \
            acc[m][n] = __builtin_amdgcn_mfma_f32_16x16x32_bf16(             \
                afr[m], bfr[n], acc[m][n], 0, 0, 0);                         \
  } while (0)

  BLOAD(0);
  ASTAGE(0, 0);
  BWRITE(0);
  BLOAD(1);
  __syncthreads();

  for (int kt = 0; kt < 32; ++kt) {
    const int buf = kt & 1;
    if (kt + 1 < 32) {
      BWRITE(buf ^ 1);
      ASTAGE(buf ^ 1, kt + 1);
      if (kt + 2 < 32) BLOAD(kt + 2);
    }
    COMPUTE(buf);
    __syncthreads();
  }
#undef BLOAD
#undef BWRITE
#undef ASTAGE
#undef COMPUTE

  const float* bias = biasAll + (size_t)e * DH;
#pragma unroll
  for (int m = 0; m < 4; ++m)
#pragma unroll
    for (int r = 0; r < 4; ++r) {
      const int row = wm + m * 16 + ks * 4 + r;
      __hip_bfloat16* orow = Hout + (size_t)(row0 + row) * DH;
#pragma unroll
      for (int n = 0; n < 4; ++n) {
        const int col = n0 + wn + n * 16 + fr;
        float v = acc[m][n][r] + bias[col];
        orow[col] = __float2bfloat16(v > 0.f ? v : 0.f);
      }
    }
}

// ---------------------------------------------------------------------------
// gemm2 body with 3-buffer counted-vmcnt pipeline (T4): raw s_barrier +
// s_waitcnt vmcnt(4) in-loop (never 0); peeled last iter drains vmcnt(0).
// Ledger: prologue stages tiles 0,1 (8 loads/wave). Iter kt: vmcnt(4)
// [tile kt's 4 landed; kt+1's 4 flying] -> barrier -> STAGE((kt+2)%3)
// [8 in flight] -> COMPUTE(kt%3). Buffer (kt+2)%3's readers finished before
// this iter's barrier; all ds_reads are consumed by MFMAs (compiler lgkm
// waits) before any wave reaches the next barrier.
// ---------------------------------------------------------------------------
static __device__ __forceinline__ void gemm2_body(
    char* smem, int b, const __hip_bfloat16* __restrict__ A,
    const __hip_bfloat16* __restrict__ B, const int* __restrict__ counts,
    float* __restrict__ Pout0) {
  auto As = reinterpret_cast<__hip_bfloat16(*)[BM][BK]>(smem);
  auto Bs = reinterpret_cast<__hip_bfloat16(*)[BN][BK]>(smem + 3 * 8192);

  const int xcd = b & 7;
  const int idx = b >> 3;
  const int grp = idx / MAXT;
  const int tile = idx - grp * MAXT;
  const int np = xcd * 2 + grp;      // 16 (ntile,kq) pairs, 2 per XCD
  const int ntile = np >> 1;
  const int kq = np & 1;
  const TileInfo ti = tile_decode(counts, tile);
  if (!ti.valid) return;
  const int e = ti.e, row0 = ti.row0;
  const int n0 = ntile * BN;
  const int kbase = kq * (DH / KSPL2);
  const int KTcnt = DH / 32;  // 128
  const int ktb = kq * 64;
  const int KTM = 64;

  const int tid = threadIdx.x;
  const int lane = tid & 63;
  const int wid = tid >> 6;
  const int lr = lane >> 2, lc = lane & 3;

  const __hip_bfloat16* aP0 =
      A + (size_t)(row0 + 32 * wid + lr) * DH + kbase + lc * 8;
  const __hip_bfloat16* aP1 =
      A + (size_t)(row0 + 32 * wid + 16 + lr) * DH + kbase + lc * 8;
  const __hip_bfloat16* bP0 =
      B + (((size_t)e * (DM / 128) + ntile) * KTcnt + ktb) * 4096 +
      wid * 1024 + lane * 8;
  const __hip_bfloat16* bP1 = bP0 + 512;

  const int wm = (wid >> 1) * 64, wn = (wid & 1) * 64;
  const int fr = lane & 15, ks = lane >> 4;

  f32x4 acc[4][4];
#pragma unroll
  for (int m = 0; m < 4; ++m)
#pragma unroll
    for (int n = 0; n < 4; ++n) acc[m][n] = (f32x4){0.f, 0.f, 0.f, 0.f};

#define STAGE(bf, kt)                                              \
  do {                                                             \
    gload16(aP0 + (size_t)(kt) * BK, &As[bf][32 * wid][0]);        \
    gload16(aP1 + (size_t)(kt) * BK, &As[bf][32 * wid + 16][0]);   \
    gload16(bP0 + (size_t)(kt) * 4096, &Bs[bf][32 * wid][0]);      \
    gload16(bP1 + (size_t)(kt) * 4096, &Bs[bf][32 * wid + 16][0]); \
  } while (0)

#define COMPUTE(bf)                                                          \
  do {                                                                       \
    bf16x8 afr[4], bfr[4];                                                   \
    _Pragma("unroll") for (int m = 0; m < 4; ++m)                            \
        afr[m] = *(const bf16x8*)&As[bf][wm + m * 16 + fr][ks * 8];          \
    _Pragma("unroll") for (int n = 0; n < 4; ++n)                            \
        bfr[n] = *(const bf16x8*)&Bs[bf][wn + n * 16 + fr][ks * 8];          \
    _Pragma("unroll") for (int m = 0; m < 4; ++m)                            \
        _Pragma("unroll") for (int n = 0; n < 4; ++n)                        \
            acc[m][n] = __builtin_amdgcn_mfma_f32_16x16x32_bf16(             \
                afr[m], bfr[n], acc[m][n], 0, 0, 0);                         \
  } while (0)

  STAGE(0, 0);
  STAGE(1, 1);
  for (int kt = 0; kt < KTM - 1; ++kt) {
    asm volatile("s_waitcnt vmcnt(4)" ::: "memory");  // tile kt landed
    __builtin_amdgcn_s_barrier();
    if (kt + 2 < KTM) STAGE((kt + 2) % 3, kt + 2);    // keep 8 in flight
    COMPUTE(kt % 3);
  }
  asm volatile("s_waitcnt vmcnt(0)" ::: "memory");    // final tile
  __builtin_amdgcn_s_barrier();
  COMPUTE((KTM - 1) % 3);
#undef STAGE
#undef COMPUTE

  float* Pout = Pout0 + (size_t)kq * MAXROWS * DM;
#pragma unroll
  for (int m = 0; m < 4; ++m)
#pragma unroll
    for (int r = 0; r < 4; ++r) {
      const int row = wm + m * 16 + ks * 4 + r;
      float* orow = Pout + (size_t)(row0 + row) * DM;
#pragma unroll
      for (int n = 0; n < 4; ++n) {
        const int col = n0 + wn + n * 16 + fr;
        orow[col] = acc[m][n][r];
      }
    }
}

// ---------------------------------------------------------------------------
// Kernel: gemm1 fp32-B (blocks 0..G1B-1) + convert w2 tiled (G1B..+8191).
// ---------------------------------------------------------------------------
__global__ __launch_bounds__(256, 2) void gemm1f_cw2_kernel(
    const __hip_bfloat16* __restrict__ xb, const float* __restrict__ w1,
    const float* __restrict__ b1, const int* __restrict__ counts,
    const int* __restrict__ bucket, __hip_bfloat16* __restrict__ h,
    const float* __restrict__ w2, __hip_bfloat16* __restrict__ w2t) {
  __shared__ __align__(16) char smem[36864];
  const int bid = blockIdx.x;
  if (bid < G1B) {
    gemm1_body_f32b(smem, bid, xb, w1, b1, counts, bucket, h);
    return;
  }
  const int id = bid - G1B;
  const int e = id >> 10;
  const int rem = id & 1023;           // 64 kg x 16 ng
  const int kglob0 = (rem >> 4) * 64;  // k slowest
  const int nglob0 = (rem & 15) * 64;  // n fastest
  convert_v4(w2 + (size_t)e * DH * DM, w2t + (size_t)e * DH * DM, DM,
             DH / 32, kglob0, nglob0, smem);
}

__global__ __launch_bounds__(256, 2) void gemm2_kernel(
    const __hip_bfloat16* __restrict__ h, const __hip_bfloat16* __restrict__ w2t,
    const int* __restrict__ counts, float* __restrict__ P) {
  __shared__ __align__(16) char smem[49152];  // 3 x (8K As + 8K Bs)
  gemm2_body(smem, blockIdx.x, h, w2t, counts, P);
}

// ---------------------------------------------------------------------------
// Reduce split-K partials, add b2, scatter padded-row -> token.
// Inline prefix from counts (no meta).
// ---------------------------------------------------------------------------
__global__ __launch_bounds__(256) void reduce_out_kernel(
    const float* __restrict__ P, const float* __restrict__ b2,
    const int* __restrict__ counts, const int* __restrict__ bucket,
    float* __restrict__ out) {
  const int gs = blockIdx.x;
  int r = 0, e = -1, i = 0, cnt_e = 0;
#pragma unroll
  for (int q = 0; q < NE; ++q) {
    const int c = counts[q];
    const int pad = ((c + BM - 1) >> 7) << 7;
    if (e < 0 && gs >= r && gs < r + pad) { e = q; i = gs - r; cnt_e = c; }
    r += pad;
  }
  if (e < 0 || i >= cnt_e) return;  // beyond total or pad row
  const int tok = bucket[e * NT + i];
  const int c = threadIdx.x * 4;
  float4 v = *(const float4*)(P + (size_t)gs * DM + c);
#pragma unroll
  for (int q = 1; q < KSPL2; ++q) {
    float4 p = *(const float4*)(P + ((size_t)q * MAXROWS + gs) * DM + c);
    v.x += p.x; v.y += p.y; v.z += p.z; v.w += p.w;
  }
  float4 b = *(const float4*)(b2 + (size_t)e * DM + c);
  v.x += b.x; v.y += b.y; v.z += b.z; v.w += b.w;
  *(float4*)(out + (size_t)tok * DM + c) = v;
}

// ---------------------------------------------------------------------------
// Fallback path (small ws): round-1 proven kernels (raw fp32 weights).
// ---------------------------------------------------------------------------
template <bool RELU_BF16>
__global__ __launch_bounds__(256, 2) void moe_gemm_fallback(
    const __hip_bfloat16* __restrict__ Aall, int lda,
    const float* __restrict__ Ball, int K, int N,
    const float* __restrict__ biasAll, const int* __restrict__ counts,
    const int* __restrict__ bucket, void* __restrict__ Out, int ldo) {
  const int e = blockIdx.z;
  const int cnt = counts[e];
  const int m0 = blockIdx.y * BM;
  if (m0 >= cnt) return;
  const int n0 = blockIdx.x * BN;

  const float* Bp = Ball + (size_t)e * K * N;
  const float* bias = biasAll + (size_t)e * N;
  const int* buck = bucket + e * NT;

  __shared__ __align__(16) __hip_bfloat16 As[2][BM][BKP];
  __shared__ __align__(16) __hip_bfloat16 Bs[2][BN][BKP];

  const int tid = threadIdx.x;
  const int lane = tid & 63;
  const int wid = tid >> 6;
  const int wm = (wid >> 1) * 64;
  const int wn = (wid & 1) * 64;
  const int fr = lane & 15;
  const int ks = lane >> 4;

  const int ar = tid >> 1;
  const int ah = tid & 1;
  const int atok = buck[min(m0 + ar, cnt - 1)];
  const __hip_bfloat16* aptr = Aall + (size_t)atok * lda + ah * 16;

  const int bc = tid & 31;
  const int bk0 = (tid >> 5) * 4;

  f32x4 acc[4][4];
#pragma unroll
  for (int m = 0; m < 4; ++m)
#pragma unroll
    for (int n = 0; n < 4; ++n) acc[m][n] = (f32x4){0.f, 0.f, 0.f, 0.f};

  const int KTf = K / BK;
  uint4 ra0, ra1;
  float rb[4][4];

  {
    const uint4* p = (const uint4*)(aptr);
    ra0 = p[0]; ra1 = p[1];
    const float* bbase = Bp + (size_t)bk0 * N + n0 + bc;
#pragma unroll
    for (int i = 0; i < 4; ++i)
#pragma unroll
      for (int j = 0; j < 4; ++j) rb[i][j] = bbase[(size_t)i * N + 32 * j];
  }
  {
    *(uint4*)&As[0][ar][ah * 16] = ra0;
    *(uint4*)&As[0][ar][ah * 16 + 8] = ra1;
#pragma unroll
    for (int j = 0; j < 4; ++j) {
      ushort4 w;
      w.x = f2bf(rb[0][j]); w.y = f2bf(rb[1][j]);
      w.z = f2bf(rb[2][j]); w.w = f2bf(rb[3][j]);
      *(ushort4*)&Bs[0][bc + 32 * j][bk0] = w;
    }
  }
  __syncthreads();

  for (int kt = 0; kt < KTf; ++kt) {
    const int buf = kt & 1;
    if (kt + 1 < KTf) {
      const uint4* p = (const uint4*)(aptr + (size_t)(kt + 1) * BK);
      ra0 = p[0]; ra1 = p[1];
      const float* bbase = Bp + (size_t)((kt + 1) * BK + bk0) * N + n0 + bc;
#pragma unroll
      for (int i = 0; i < 4; ++i)
#pragma unroll
        for (int j = 0; j < 4; ++j) rb[i][j] = bbase[(size_t)i * N + 32 * j];
    }

    bf16x8 afr[4], bfr[4];
#pragma unroll
    for (int m = 0; m < 4; ++m)
      afr[m] = *(const bf16x8*)&As[buf][wm + m * 16 + fr][ks * 8];
#pragma unroll
    for (int n = 0; n < 4; ++n)
      bfr[n] = *(const bf16x8*)&Bs[buf][wn + n * 16 + fr][ks * 8];
#pragma unroll
    for (int m = 0; m < 4; ++m)
#pragma unroll
      for (int n = 0; n < 4; ++n)
        acc[m][n] = __builtin_amdgcn_mfma_f32_16x16x32_bf16(afr[m], bfr[n],
                                                            acc[m][n], 0, 0, 0);

    __syncthreads();
    if (kt + 1 < KTf) {
      *(uint4*)&As[buf ^ 1][ar][ah * 16] = ra0;
      *(uint4*)&As[buf ^ 1][ar][ah * 16 + 8] = ra1;
#pragma unroll
      for (int j = 0; j < 4; ++j) {
        ushort4 w;
        w.x = f2bf(rb[0][j]); w.y = f2bf(rb[1][j]);
        w.z = f2bf(rb[2][j]); w.w = f2bf(rb[3][j]);
        *(ushort4*)&Bs[buf ^ 1][bc + 32 * j][bk0] = w;
      }
      __syncthreads();
    }
  }

  float* outF = (float*)Out;
  __hip_bfloat16* outB = (__hip_bfloat16*)Out;
#pragma unroll
  for (int m = 0; m < 4; ++m) {
#pragma unroll
    for (int r = 0; r < 4; ++r) {
      const int row = wm + m * 16 + ks * 4 + r;
      const int slot = m0 + row;
      if (slot < cnt) {
        const int tok = buck[slot];
#pragma unroll
        for (int n = 0; n < 4; ++n) {
          const int col = n0 + wn + n * 16 + fr;
          float v = acc[m][n][r] + bias[col];
          if (RELU_BF16) {
            v = v > 0.f ? v : 0.f;
            outB[(size_t)tok * ldo + col] = __float2bfloat16(v);
          } else {
            outF[(size_t)tok * ldo + col] = v;
          }
        }
      }
    }
  }
}

extern "C" void kernel_launch(void* const* d_in, const int* in_sizes, int n_in,
                              void* d_out, int out_size, void* d_ws,
                              size_t ws_size, hipStream_t stream) {
  const float* x = (const float*)d_in[0];
  const float* gw = (const float*)d_in[1];
  const float* gb = (const float*)d_in[2];
  const float* w1 = (const float*)d_in[3];
  const float* b1 = (const float*)d_in[4];
  const float* w2 = (const float*)d_in[5];
  const float* b2 = (const float*)d_in[6];
  (void)in_sizes; (void)n_in; (void)out_size;

  char* ws = (char*)d_ws;
  int* counts = (int*)ws;
  int* bucket = (int*)(ws + O_BUCKET);
  __hip_bfloat16* xb = (__hip_bfloat16*)(ws + O_XB);
  __hip_bfloat16* h = (__hip_bfloat16*)(ws + O_H);

  hipMemsetAsync(ws, 0, 1024, stream);

  if (ws_size >= WS_NEED) {
    __hip_bfloat16* w2t = (__hip_bfloat16*)(ws + O_W2T);
    float* P = (float*)(ws + O_P);

    gate_route_kernel<<<NT / 4, 256, 0, stream>>>(x, gw, gb, counts, bucket,
                                                  xb);
    gemm1f_cw2_kernel<<<G1B + 8192, 256, 0, stream>>>(
        xb, w1, b1, counts, bucket, h, w2, w2t);
    gemm2_kernel<<<8 * 2 * MAXT, 256, 0, stream>>>(h, w2t, counts, P);
    reduce_out_kernel<<<MAXROWS, 256, 0, stream>>>(P, b2, counts, bucket,
                                                   (float*)d_out);
  } else {
    gate_route_kernel<<<NT / 4, 256, 0, stream>>>(x, gw, gb, counts, bucket,
                                                  xb);
    dim3 g1(DH / BN, NT / BM, NE);
    moe_gemm_fallback<true><<<g1, 256, 0, stream>>>(
        xb, DM, w1, DM, DH, b1, counts, bucket, (void*)h, DH);
    dim3 g2(DM / BN, NT / BM, NE);
    moe_gemm_fallback<false><<<g2, 256, 0, stream>>>(
        h, DH, w2, DH, DM, b2, counts, bucket, d_out, DM);
  }
}